// Round 2
// baseline (12849.557 us; speedup 1.0000x reference)
//
#include <hip/hip_runtime.h>
#include <hip/hip_bf16.h>

// BiLSTM-CRF forward, MI355X gfx950.
// Shapes: B=256, S=512, E=256, H=256, G=4H=1024, T=32, PAD=49999.
//
// Pipeline (workspace-lean: ~98 MB):
//   K0 cvt_weights : fp32 -> bf16 for W_ih (2x), W_hh (2x), W_out
//   K1 embed_gather: x_bf[b][s][e] only (reversal handled inside K2 by index math)
//   K2 lstm_rec    : 32 WGs x 512 thr; WG = (16 sentences, 1 direction);
//                    per step: gates = b + x(s_eff) @ W_ih^T + h @ W_hh^T via MFMA,
//                    W_ih/W_hh streamed from L2; h via LDS double buffer;
//                    fused emission = h @ W_out_half^T written at unreversed pos
//   K3 crf_kernel  : per-sentence real-path score + CRF forward (logsumexp over T=32)

typedef __bf16 bf16x8 __attribute__((ext_vector_type(8)));
typedef float f32x4 __attribute__((ext_vector_type(4)));
typedef unsigned int uint4v __attribute__((ext_vector_type(4)));

__device__ __forceinline__ unsigned short f2bf(float f) {
  union { float f; unsigned int u; } v; v.f = f;
  unsigned int r = v.u + 0x7fffu + ((v.u >> 16) & 1u);   // RNE
  return (unsigned short)(r >> 16);
}
__device__ __forceinline__ float fsig(float x) {
  float e = __builtin_amdgcn_exp2f(-1.4426950408889634f * x);
  return __builtin_amdgcn_rcpf(1.0f + e);
}
__device__ __forceinline__ float ftanh(float x) {
  float e = __builtin_amdgcn_exp2f(2.8853900817779268f * x);  // exp2(2x*log2e)
  return 1.0f - 2.0f * __builtin_amdgcn_rcpf(e + 1.0f);
}

// ---------------- K0: weight conversion fp32 -> bf16 ----------------
__global__ void cvt_weights(const float* __restrict__ wih_f, const float* __restrict__ wih_b,
                            const float* __restrict__ whh_f, const float* __restrict__ whh_b,
                            const float* __restrict__ wo,
                            unsigned short* __restrict__ wih, unsigned short* __restrict__ whh,
                            unsigned short* __restrict__ wout) {
  int t = blockIdx.x * 256 + threadIdx.x;
  int i = t * 4;
  const float* src; unsigned short* dst; int off;
  if (i < 524288)       { src = (i < 262144) ? wih_f : wih_b; off = i & 262143; dst = wih + i; }
  else if (i < 1048576) { int k = i - 524288;  src = (k < 262144) ? whh_f : whh_b; off = k & 262143; dst = whh + k; }
  else if (i < 1064960) { int k = i - 1048576; src = wo; off = k; dst = wout + k; }
  else return;
  f32x4 v = *(const f32x4*)(src + off);
  uint2 p;
  p.x = f2bf(v[0]) | ((unsigned int)f2bf(v[1]) << 16);
  p.y = f2bf(v[2]) | ((unsigned int)f2bf(v[3]) << 16);
  *(uint2*)dst = p;
}

// ---------------- K1: embedding gather -> bf16 ----------------
__global__ void embed_gather(const float* __restrict__ emb, const int* __restrict__ sent,
                             unsigned short* __restrict__ xo) {
  int tok  = blockIdx.x * 4 + (threadIdx.x >> 6);   // b*512+s
  int lane = threadIdx.x & 63;
  int tkn = sent[tok];
  f32x4 v = *(const f32x4*)(emb + (size_t)tkn * 256 + lane * 4);
  uint2 o;
  o.x = f2bf(v[0]) | ((unsigned int)f2bf(v[1]) << 16);
  o.y = f2bf(v[2]) | ((unsigned int)f2bf(v[3]) << 16);
  *(uint2*)(xo + (size_t)tok * 256 + lane * 4) = o;
}

// ---------------- K2: fused LSTM recurrence (input proj + recurrence + emission) --
// grid 32: block = (group of 16 sentences) x (direction). 512 threads = 8 waves.
// Wave w owns gate rows {g*256 + w*32 + a*16 .. +16 : g in 0..3, a in 0..1}.
// Per step: acc = bias; acc += W_ih @ x(s_eff)^T (K=256); acc += W_hh @ h^T (K=256);
// gate nonlinearities -> h to LDS; fused emit by waves 0-1.
__global__ __launch_bounds__(512, 1) void lstm_rec(
    const unsigned short* __restrict__ x_bf,   // [256][512][256]
    const unsigned short* __restrict__ wih,    // [2][1024][256]
    const unsigned short* __restrict__ whh,    // [2][1024][256]
    const unsigned short* __restrict__ wout,   // [32][512]
    const float* __restrict__ bih_f, const float* __restrict__ bhh_f,
    const float* __restrict__ bih_b, const float* __restrict__ bhh_b,
    const float* __restrict__ bout,
    const int* __restrict__ lens,
    float* __restrict__ emit_f, float* __restrict__ emit_b)  // each [256][512][32]
{
  __shared__ __align__(16) unsigned short hbuf[2][16 * 264];
  int bx = blockIdx.x;
  int dir = bx & 1, grp = bx >> 1, b0 = grp * 16;
  int tid = threadIdx.x, w = tid >> 6, lane = tid & 63, col = lane & 15, q = lane >> 4;
  int mylen  = lens[b0 + col];
  int maxlen = lens[b0];              // lengths sorted descending -> group max
  const unsigned short* wihb = wih + (size_t)dir * 262144;
  const unsigned short* whhb = whh + (size_t)dir * 262144;
  const float* bi = dir ? bih_b : bih_f;
  const float* bh = dir ? bhh_b : bhh_f;

  // acc init value per tile: bias_sum[row0 + q*4 + r], row0 = (t&3)*256 + w*32 + (t>>2)*16
  f32x4 bias4[8];
#pragma unroll
  for (int t = 0; t < 8; t++) {
    int row0 = (t & 3) * 256 + w * 32 + (t >> 2) * 16;
#pragma unroll
    for (int r = 0; r < 4; r++)
      bias4[t][r] = bi[row0 + q * 4 + r] + bh[row0 + q * 4 + r];
  }

  bf16x8 hf[8];
#pragma unroll
  for (int i = 0; i < 8; i++) hf[i] = __builtin_bit_cast(bf16x8, (uint4v){0u, 0u, 0u, 0u});
  float c0[8];
#pragma unroll
  for (int i = 0; i < 8; i++) c0[i] = 0.f;

  bf16x8 wof[8];
  float bo[4] = {0.f, 0.f, 0.f, 0.f};
  if (w < 2) {
    const unsigned short* wp = wout + (size_t)(w * 16 + col) * 512 + dir * 256;
#pragma unroll
    for (int kt = 0; kt < 8; kt++) wof[kt] = *(const bf16x8*)(wp + kt * 32 + q * 8);
#pragma unroll
    for (int r = 0; r < 4; r++) bo[r] = dir ? 0.f : bout[w * 16 + q * 4 + r];
  }
  float* ebase = dir ? emit_b : emit_f;

  for (int s = 0; s < maxlen; s++) {
    f32x4 acc[8];
#pragma unroll
    for (int t = 0; t < 8; t++) acc[t] = bias4[t];

    // ---- x-part: acc += W_ih @ x(s_eff)^T ----
    int s_eff = dir ? ((s < mylen) ? (mylen - 1 - s) : s) : s;
    const unsigned short* xp = x_bf + ((size_t)(b0 + col) * 512 + s_eff) * 256;
#pragma unroll
    for (int kt = 0; kt < 8; kt++) {
      bf16x8 xb = *(const bf16x8*)(xp + kt * 32 + q * 8);
#pragma unroll
      for (int t = 0; t < 8; t++) {
        int row0 = (t & 3) * 256 + w * 32 + (t >> 2) * 16;
        bf16x8 af = *(const bf16x8*)(wihb + (size_t)(row0 + col) * 256 + kt * 32 + q * 8);
        acc[t] = __builtin_amdgcn_mfma_f32_16x16x32_bf16(af, xb, acc[t], 0, 0, 0);
      }
    }
    // ---- h-part: acc += W_hh @ h^T ----
#pragma unroll
    for (int kt = 0; kt < 8; kt++) {
      bf16x8 hb = hf[kt];
#pragma unroll
      for (int t = 0; t < 8; t++) {
        int row0 = (t & 3) * 256 + w * 32 + (t >> 2) * 16;
        bf16x8 af = *(const bf16x8*)(whhb + (size_t)(row0 + col) * 256 + kt * 32 + q * 8);
        acc[t] = __builtin_amdgcn_mfma_f32_16x16x32_bf16(af, hb, acc[t], 0, 0, 0);
      }
    }

    // gate nonlinearities; write h (bf16) into LDS exchange buffer
    unsigned short* hrow = hbuf[s & 1] + col * 264;
#pragma unroll
    for (int a = 0; a < 2; a++) {
      float hv[4];
#pragma unroll
      for (int r = 0; r < 4; r++) {
        float ig = acc[a * 4 + 0][r], fg = acc[a * 4 + 1][r];
        float gg = acc[a * 4 + 2][r], og = acc[a * 4 + 3][r];
        float cn = fsig(fg) * c0[a * 4 + r] + fsig(ig) * ftanh(gg);
        c0[a * 4 + r] = cn;
        hv[r] = fsig(og) * ftanh(cn);
      }
      uint2 hp;
      hp.x = f2bf(hv[0]) | ((unsigned int)f2bf(hv[1]) << 16);
      hp.y = f2bf(hv[2]) | ((unsigned int)f2bf(hv[3]) << 16);
      *(uint2*)(hrow + w * 32 + a * 16 + q * 4) = hp;
    }
    __syncthreads();
    const unsigned short* hrd = hbuf[s & 1] + col * 264;
#pragma unroll
    for (int kt = 0; kt < 8; kt++)
      hf[kt] = *(const bf16x8*)(hrd + kt * 32 + q * 8);

    if (w < 2) {  // fused emission: D[tag][sentence] = W_out_half @ h^T
      f32x4 ea = (f32x4){0.f, 0.f, 0.f, 0.f};
#pragma unroll
      for (int kt = 0; kt < 8; kt++)
        ea = __builtin_amdgcn_mfma_f32_16x16x32_bf16(wof[kt], hf[kt], ea, 0, 0, 0);
      if (s < mylen) {
        int pos = dir ? (mylen - 1 - s) : s;
        float* dst = ebase + (((size_t)(b0 + col) * 512 + pos) * 32 + w * 16 + q * 4);
        f32x4 r = ea;
        r[0] += bo[0]; r[1] += bo[1]; r[2] += bo[2]; r[3] += bo[3];
        *(f32x4*)dst = r;
      }
    }
  }
}

// ---------------- K3: real-path score + CRF forward ----------------
// 256 blocks x 64 threads; one sentence per block. j = lane&31 (tag), halves split i.
__global__ void crf_kernel(const float* __restrict__ emit_f, const float* __restrict__ emit_b,
                           const float* __restrict__ trans, const int* __restrict__ tags,
                           const int* __restrict__ lens, float* __restrict__ out) {
  const float LOG2E = 1.4426950408889634f, LN2 = 0.6931471805599453f;
  int b = blockIdx.x, lane = threadIdx.x;
  int len = lens[b];
  const int* tg = tags + b * 512;

  float rs = 0.f;
  for (int s = lane; s < len; s += 64) {
    int t1 = tg[s];
    float e = emit_f[((size_t)b * 512 + s) * 32 + t1] + emit_b[((size_t)b * 512 + s) * 32 + t1];
    if (s > 0) e += trans[tg[s - 1] * 32 + t1];
    rs += e;
  }
#pragma unroll
  for (int m = 32; m; m >>= 1) rs += __shfl_xor(rs, m);

  int j = lane & 31, half = lane >> 5, i0 = half * 16;
  float tr[16];
#pragma unroll
  for (int ii = 0; ii < 16; ii++) tr[ii] = trans[(i0 + ii) * 32 + j];
  float alpha = emit_f[(size_t)b * 512 * 32 + j] + emit_b[(size_t)b * 512 * 32 + j];
  for (int s = 1; s < len; s++) {
    float e = emit_f[((size_t)b * 512 + s) * 32 + j] + emit_b[((size_t)b * 512 + s) * 32 + j];
    float v[16]; float m1 = -1e30f;
#pragma unroll
    for (int ii = 0; ii < 16; ii++) { v[ii] = __shfl(alpha, i0 + ii) + tr[ii]; m1 = fmaxf(m1, v[ii]); }
    float m2 = fmaxf(m1, __shfl_xor(m1, 32));
    float sum = 0.f;
#pragma unroll
    for (int ii = 0; ii < 16; ii++) sum += __builtin_amdgcn_exp2f((v[ii] - m2) * LOG2E);
    sum += __shfl_xor(sum, 32);
    alpha = m2 + LN2 * __builtin_amdgcn_logf(sum) + e;   // amdgcn logf == log2
  }
  float mz = alpha;
#pragma unroll
  for (int m = 16; m; m >>= 1) mz = fmaxf(mz, __shfl_xor(mz, m));
  float sz = __builtin_amdgcn_exp2f((alpha - mz) * LOG2E);
#pragma unroll
  for (int m = 16; m; m >>= 1) sz += __shfl_xor(sz, m);
  float logz = mz + LN2 * __builtin_amdgcn_logf(sz);
  if (lane == 0) out[b] = logz - rs;
}

// ---------------- launch ----------------
extern "C" void kernel_launch(void* const* d_in, const int* in_sizes, int n_in,
                              void* d_out, int out_size, void* d_ws, size_t ws_size,
                              hipStream_t stream) {
  const float* emb   = (const float*)d_in[0];
  const float* Wih_f = (const float*)d_in[1];
  const float* Whh_f = (const float*)d_in[2];
  const float* bih_f = (const float*)d_in[3];
  const float* bhh_f = (const float*)d_in[4];
  const float* Wih_b = (const float*)d_in[5];
  const float* Whh_b = (const float*)d_in[6];
  const float* bih_b = (const float*)d_in[7];
  const float* bhh_b = (const float*)d_in[8];
  const float* Wout  = (const float*)d_in[9];
  const float* bout  = (const float*)d_in[10];
  const float* trans = (const float*)d_in[11];
  const int* sent = (const int*)d_in[12];
  const int* tags = (const int*)d_in[13];
  const int* lens = (const int*)d_in[14];
  float* out = (float*)d_out;

  // workspace layout (bytes), total 102,793,216 (~98 MB)
  char* ws = (char*)d_ws;
  if (ws_size < 102793216ull) return;
  unsigned short* x_bf   = (unsigned short*)(ws);                 // 67,108,864
  float*          emit_f = (float*)(ws + 67108864);               // 16,777,216
  float*          emit_b = (float*)(ws + 83886080);               // 16,777,216
  unsigned short* wih_bf = (unsigned short*)(ws + 100663296);     //  1,048,576
  unsigned short* whh_bf = (unsigned short*)(ws + 101711872);     //  1,048,576
  unsigned short* wout_bf= (unsigned short*)(ws + 102760448);     //     32,768

  cvt_weights<<<1040, 256, 0, stream>>>(Wih_f, Wih_b, Whh_f, Whh_b, Wout,
                                        wih_bf, whh_bf, wout_bf);
  embed_gather<<<32768, 256, 0, stream>>>(emb, sent, x_bf);
  lstm_rec<<<32, 512, 0, stream>>>(x_bf, wih_bf, whh_bf, wout_bf,
                                   bih_f, bhh_f, bih_b, bhh_b, bout, lens,
                                   emit_f, emit_b);
  crf_kernel<<<256, 64, 0, stream>>>(emit_f, emit_b, trans, tags, lens, out);
}

// Round 3
// 3499.297 us; speedup vs baseline: 3.6720x; 3.6720x over previous
//
#include <hip/hip_runtime.h>
#include <hip/hip_bf16.h>

// BiLSTM-CRF forward, MI355X gfx950.
// B=256, S=512, E=256, H=256, G=4H=1024, T=32, PAD=49999.
//
// Pipeline (chunked over S to fit workspace; chunkS picked from ws_size):
//   K0 cvt_weights   : fp32 -> bf16 for W_ih(2), W_hh(2), W_out
//   per chunk c:
//     K1 gx_gemm     : gx[dir][s_local][b][g] = W_ih @ emb[sent[b][s_eff]] + bias (bf16)
//                      (embedding gathered+converted in-kernel; no x_bf buffer)
//     K2 lstm_rec    : 32 WGs; WG=(16 sentences, 1 dir); W_hh slice resident:
//                      32 frags in VGPRs + 16 frags in LDS + 16 streamed from L2/step.
//                      h via LDS double buffer; fused emission on waves 0-1.
//                      (h,c) state persisted in global between chunks.
//   K3 crf_kernel    : real-path score + CRF forward (T=32) per sentence.

typedef __bf16 bf16x8 __attribute__((ext_vector_type(8)));
typedef float f32x4 __attribute__((ext_vector_type(4)));
typedef unsigned int uint4v __attribute__((ext_vector_type(4)));

__device__ __forceinline__ unsigned short f2bf(float f) {
  union { float f; unsigned int u; } v; v.f = f;
  unsigned int r = v.u + 0x7fffu + ((v.u >> 16) & 1u);   // RNE
  return (unsigned short)(r >> 16);
}
__device__ __forceinline__ float bf2f(unsigned int lo16) {
  union { unsigned int u; float f; } v; v.u = lo16 << 16;
  return v.f;
}
__device__ __forceinline__ float fsig(float x) {
  float e = __builtin_amdgcn_exp2f(-1.4426950408889634f * x);
  return __builtin_amdgcn_rcpf(1.0f + e);
}
__device__ __forceinline__ float ftanh(float x) {
  float e = __builtin_amdgcn_exp2f(2.8853900817779268f * x);
  return 1.0f - 2.0f * __builtin_amdgcn_rcpf(e + 1.0f);
}

// ---------------- K0: weight conversion fp32 -> bf16 ----------------
__global__ void cvt_weights(const float* __restrict__ wih_f, const float* __restrict__ wih_b,
                            const float* __restrict__ whh_f, const float* __restrict__ whh_b,
                            const float* __restrict__ wo,
                            unsigned short* __restrict__ wih, unsigned short* __restrict__ whh,
                            unsigned short* __restrict__ wout) {
  int t = blockIdx.x * 256 + threadIdx.x;
  int i = t * 4;
  const float* src; unsigned short* dst; int off;
  if (i < 524288)       { src = (i < 262144) ? wih_f : wih_b; off = i & 262143; dst = wih + i; }
  else if (i < 1048576) { int k = i - 524288;  src = (k < 262144) ? whh_f : whh_b; off = k & 262143; dst = whh + k; }
  else if (i < 1064960) { int k = i - 1048576; src = wo; off = k; dst = wout + k; }
  else return;
  f32x4 v = *(const f32x4*)(src + off);
  uint2 p;
  p.x = f2bf(v[0]) | ((unsigned int)f2bf(v[1]) << 16);
  p.y = f2bf(v[2]) | ((unsigned int)f2bf(v[3]) << 16);
  *(uint2*)dst = p;
}

// ---------------- K1: gx = W_ih @ x(s_eff)^T + bias, bf16 out ----------------
// grid (chunkS*2, 2): x = (s_local, 128-sentence tile), y = dir. 512 thr = 8 waves.
// Embedding rows gathered fp32 -> bf16 in-kernel (no x_bf staging buffer).
__global__ __launch_bounds__(512, 2) void gx_gemm(
    const float* __restrict__ emb, const int* __restrict__ sent, const int* __restrict__ lens,
    const unsigned short* __restrict__ wih,     // [2][1024][256] bf16
    const float* __restrict__ bih_f, const float* __restrict__ bhh_f,
    const float* __restrict__ bih_b, const float* __restrict__ bhh_b,
    unsigned short* __restrict__ gx,            // [2][chunkS][256][1024] bf16
    int s0, int chunkS)
{
  __shared__ __align__(16) unsigned short wtile[128 * 264];  // +8 pad
  __shared__ __align__(16) float btile[128];
  int dir = blockIdx.y;
  int bx  = blockIdx.x;
  int s_local = bx >> 1;
  int s = s0 + s_local;
  int bbase = (bx & 1) * 128;
  int tid = threadIdx.x, w = tid >> 6, lane = tid & 63, col = lane & 15, q = lane >> 4;
  const float* bi = dir ? bih_b : bih_f;
  const float* bh = dir ? bhh_b : bhh_f;
  int bidx = bbase + w * 16 + col;
  int len = lens[bidx];
  int s_eff = dir ? ((s < len) ? (len - 1 - s) : s) : s;
  int token = sent[bidx * 512 + s_eff];

  // B-fragments: embedding row fp32 -> bf16
  bf16x8 xf[8];
  const float* ep = emb + (size_t)token * 256;
#pragma unroll
  for (int kt = 0; kt < 8; kt++) {
    f32x4 a0 = *(const f32x4*)(ep + kt * 32 + q * 8);
    f32x4 a1 = *(const f32x4*)(ep + kt * 32 + q * 8 + 4);
    uint4v pk;
    pk[0] = f2bf(a0[0]) | ((unsigned int)f2bf(a0[1]) << 16);
    pk[1] = f2bf(a0[2]) | ((unsigned int)f2bf(a0[3]) << 16);
    pk[2] = f2bf(a1[0]) | ((unsigned int)f2bf(a1[1]) << 16);
    pk[3] = f2bf(a1[2]) | ((unsigned int)f2bf(a1[3]) << 16);
    xf[kt] = __builtin_bit_cast(bf16x8, pk);
  }

  const unsigned short* wsrc = wih + (size_t)dir * 262144;
  for (int c = 0; c < 8; c++) {
    int n0 = c * 128;
#pragma unroll
    for (int it = 0; it < 8; it++) {
      int seg = it * 512 + tid;
      int row = seg >> 5;
      int kc  = (seg & 31) * 8;
      *(uint4v*)(wtile + row * 264 + kc) = *(const uint4v*)(wsrc + (size_t)(n0 + row) * 256 + kc);
    }
    if (tid < 128) btile[tid] = bi[n0 + tid] + bh[n0 + tid];
    __syncthreads();

    f32x4 acc[8];
#pragma unroll
    for (int nt = 0; nt < 8; nt++) acc[nt] = (f32x4){0.f, 0.f, 0.f, 0.f};
#pragma unroll
    for (int kt = 0; kt < 8; kt++) {
      bf16x8 xb = xf[kt];
#pragma unroll
      for (int nt = 0; nt < 8; nt++) {
        bf16x8 af = *(const bf16x8*)(wtile + (nt * 16 + col) * 264 + kt * 32 + q * 8);
        acc[nt] = __builtin_amdgcn_mfma_f32_16x16x32_bf16(af, xb, acc[nt], 0, 0, 0);
      }
    }
#pragma unroll
    for (int nt = 0; nt < 8; nt++) {
      f32x4 bias = *(const f32x4*)(btile + nt * 16 + q * 4);
      f32x4 r = acc[nt];
      r[0] += bias[0]; r[1] += bias[1]; r[2] += bias[2]; r[3] += bias[3];
      uint2 pk;
      pk.x = f2bf(r[0]) | ((unsigned int)f2bf(r[1]) << 16);
      pk.y = f2bf(r[2]) | ((unsigned int)f2bf(r[3]) << 16);
      size_t off = (((size_t)dir * chunkS + s_local) * 256 + bidx) * 1024 + n0 + nt * 16 + q * 4;
      *(uint2*)(gx + off) = pk;
    }
    __syncthreads();
  }
}

// ---------------- K2: LSTM recurrence chunk, W_hh on-chip resident ----------------
// grid 32: WG = (16 sentences, 1 dir), 512 thr = 8 waves. Wave w owns gate rows
// {(t&3)*256 + w*32 + (t>>2)*16 + col}. W_hh frags: kt 0..3 regs, 4..5 LDS, 6..7 L2.
// Dynamic LDS: 128 KB wlds + 16.9 KB hbuf = 147,968 B.
__global__ __launch_bounds__(512, 2) void lstm_rec(
    const unsigned short* __restrict__ gx,     // [2][chunkS][256][1024]
    const unsigned short* __restrict__ whh,    // [2][1024][256]
    const unsigned short* __restrict__ wout,   // [32][512]
    const float* __restrict__ bout,
    const int* __restrict__ lens,
    float* __restrict__ emit_f, float* __restrict__ emit_b,   // [256][512][32]
    unsigned short* __restrict__ h_state,      // [2][256][256] bf16
    float* __restrict__ c_state,               // [2][256][256] f32
    int s0, int chunkS, int first)
{
  extern __shared__ __align__(16) unsigned short SH[];  // wlds: SH[0..65535], hbuf: SH+65536
  int bx = blockIdx.x;
  int dir = bx & 1, grp = bx >> 1, b0 = grp * 16;
  int tid = threadIdx.x, w = tid >> 6, lane = tid & 63, col = lane & 15, q = lane >> 4;
  int maxlen = lens[b0];              // lengths sorted descending -> group max
  if (s0 >= maxlen) return;
  int mylen = lens[b0 + col];
  int send  = s0 + chunkS; if (send > maxlen) send = maxlen;
  const unsigned short* whhb = whh + (size_t)dir * 262144;
  unsigned short* hbufb = SH + 65536;   // 2 buffers of 16*264 shorts (4224 each)

  // ---- W_hh fragments: kt 0..3 -> registers ----
  bf16x8 wreg[32];
#pragma unroll
  for (int kt = 0; kt < 4; kt++)
#pragma unroll
    for (int t = 0; t < 8; t++) {
      int row0 = (t & 3) * 256 + w * 32 + (t >> 2) * 16;
      wreg[kt * 8 + t] = *(const bf16x8*)(whhb + (size_t)(row0 + col) * 256 + kt * 32 + q * 8);
    }
  // ---- kt 4..5 -> LDS (per-wave region, lane*16B contiguous: conflict-free b128) ----
#pragma unroll
  for (int kt = 4; kt < 6; kt++)
#pragma unroll
    for (int t = 0; t < 8; t++) {
      int row0 = (t & 3) * 256 + w * 32 + (t >> 2) * 16;
      bf16x8 f = *(const bf16x8*)(whhb + (size_t)(row0 + col) * 256 + kt * 32 + q * 8);
      *(bf16x8*)(SH + w * 8192 + ((kt - 4) * 8 + t) * 512 + lane * 8) = f;
    }

  // ---- emission weights (waves 0-1) ----
  bf16x8 wof[8];
  float bo[4] = {0.f, 0.f, 0.f, 0.f};
  if (w < 2) {
    const unsigned short* wp = wout + (size_t)(w * 16 + col) * 512 + dir * 256;
#pragma unroll
    for (int kt = 0; kt < 8; kt++) wof[kt] = *(const bf16x8*)(wp + kt * 32 + q * 8);
#pragma unroll
    for (int r = 0; r < 4; r++) bo[r] = dir ? 0.f : bout[w * 16 + q * 4 + r];
  }
  float* ebase = dir ? emit_b : emit_f;

  // ---- state init: c regs + h into hbuf[(s0+1)&1] ----
  float c0[8];
  int pf = (s0 + 1) & 1;
  unsigned short* hini = hbufb + pf * 4224 + col * 264 + w * 32;
  size_t stoff = ((size_t)(dir * 256 + b0 + col)) * 256 + w * 32;
  if (first) {
#pragma unroll
    for (int i = 0; i < 8; i++) c0[i] = 0.f;
    *(uint2*)(hini + q * 4)      = (uint2){0u, 0u};
    *(uint2*)(hini + 16 + q * 4) = (uint2){0u, 0u};
  } else {
#pragma unroll
    for (int a = 0; a < 2; a++) {
      f32x4 cv = *(const f32x4*)(c_state + stoff + a * 16 + q * 4);
#pragma unroll
      for (int r = 0; r < 4; r++) c0[a * 4 + r] = cv[r];
      *(uint2*)(hini + a * 16 + q * 4) = *(const uint2*)(h_state + stoff + a * 16 + q * 4);
    }
  }
  __syncthreads();

  for (int s = s0; s < send; s++) {
    // acc init from gx (bias already folded in)
    const unsigned short* gxs = gx + (((size_t)dir * chunkS + (s - s0)) * 256 + b0 + col) * 1024;
    f32x4 acc[8];
#pragma unroll
    for (int t = 0; t < 8; t++) {
      int row0 = (t & 3) * 256 + w * 32 + (t >> 2) * 16;
      uint2 gv = *(const uint2*)(gxs + row0 + q * 4);
      f32x4 a;
      a[0] = bf2f(gv.x & 0xffffu); a[1] = bf2f(gv.x >> 16);
      a[2] = bf2f(gv.y & 0xffffu); a[3] = bf2f(gv.y >> 16);
      acc[t] = a;
    }
    const unsigned short* hrd = hbufb + ((s + 1) & 1) * 4224 + col * 264;
#pragma unroll
    for (int kt = 0; kt < 8; kt++) {
      bf16x8 hb = *(const bf16x8*)(hrd + kt * 32 + q * 8);
#pragma unroll
      for (int t = 0; t < 8; t++) {
        int row0 = (t & 3) * 256 + w * 32 + (t >> 2) * 16;
        bf16x8 af;
        if (kt < 4)      af = wreg[kt * 8 + t];
        else if (kt < 6) af = *(const bf16x8*)(SH + w * 8192 + ((kt - 4) * 8 + t) * 512 + lane * 8);
        else             af = *(const bf16x8*)(whhb + (size_t)(row0 + col) * 256 + kt * 32 + q * 8);
        acc[t] = __builtin_amdgcn_mfma_f32_16x16x32_bf16(af, hb, acc[t], 0, 0, 0);
      }
    }
    // gate nonlinearities -> h (bf16) into LDS
    unsigned short* hrow = hbufb + (s & 1) * 4224 + col * 264;
#pragma unroll
    for (int a = 0; a < 2; a++) {
      float hv[4];
#pragma unroll
      for (int r = 0; r < 4; r++) {
        float ig = acc[a * 4 + 0][r], fg = acc[a * 4 + 1][r];
        float gg = acc[a * 4 + 2][r], og = acc[a * 4 + 3][r];
        float cn = fsig(fg) * c0[a * 4 + r] + fsig(ig) * ftanh(gg);
        c0[a * 4 + r] = cn;
        hv[r] = fsig(og) * ftanh(cn);
      }
      uint2 hp;
      hp.x = f2bf(hv[0]) | ((unsigned int)f2bf(hv[1]) << 16);
      hp.y = f2bf(hv[2]) | ((unsigned int)f2bf(hv[3]) << 16);
      *(uint2*)(hrow + w * 32 + a * 16 + q * 4) = hp;
    }
    __syncthreads();

    if (w < 2) {  // fused emission: D[tag][sentence] = W_out_half @ h^T
      const unsigned short* hrd2 = hbufb + (s & 1) * 4224 + col * 264;
      f32x4 ea = (f32x4){0.f, 0.f, 0.f, 0.f};
#pragma unroll
      for (int kt = 0; kt < 8; kt++) {
        bf16x8 hb2 = *(const bf16x8*)(hrd2 + kt * 32 + q * 8);
        ea = __builtin_amdgcn_mfma_f32_16x16x32_bf16(wof[kt], hb2, ea, 0, 0, 0);
      }
      if (s < mylen) {
        int pos = dir ? (mylen - 1 - s) : s;
        float* dst = ebase + (((size_t)(b0 + col) * 512 + pos) * 32 + w * 16 + q * 4);
        f32x4 r = ea;
        r[0] += bo[0]; r[1] += bo[1]; r[2] += bo[2]; r[3] += bo[3];
        *(f32x4*)dst = r;
      }
    }
  }

  // ---- persist state for next chunk ----
  const unsigned short* hfin = hbufb + ((send - 1) & 1) * 4224 + col * 264 + w * 32;
#pragma unroll
  for (int a = 0; a < 2; a++) {
    f32x4 cv;
#pragma unroll
    for (int r = 0; r < 4; r++) cv[r] = c0[a * 4 + r];
    *(f32x4*)(c_state + stoff + a * 16 + q * 4) = cv;
    *(uint2*)(h_state + stoff + a * 16 + q * 4) = *(const uint2*)(hfin + a * 16 + q * 4);
  }
}

// ---------------- K3: real-path score + CRF forward ----------------
__global__ void crf_kernel(const float* __restrict__ emit_f, const float* __restrict__ emit_b,
                           const float* __restrict__ trans, const int* __restrict__ tags,
                           const int* __restrict__ lens, float* __restrict__ out) {
  const float LOG2E = 1.4426950408889634f, LN2 = 0.6931471805599453f;
  int b = blockIdx.x, lane = threadIdx.x;
  int len = lens[b];
  const int* tg = tags + b * 512;

  float rs = 0.f;
  for (int s = lane; s < len; s += 64) {
    int t1 = tg[s];
    float e = emit_f[((size_t)b * 512 + s) * 32 + t1] + emit_b[((size_t)b * 512 + s) * 32 + t1];
    if (s > 0) e += trans[tg[s - 1] * 32 + t1];
    rs += e;
  }
#pragma unroll
  for (int m = 32; m; m >>= 1) rs += __shfl_xor(rs, m);

  int j = lane & 31, half = lane >> 5, i0 = half * 16;
  float tr[16];
#pragma unroll
  for (int ii = 0; ii < 16; ii++) tr[ii] = trans[(i0 + ii) * 32 + j];
  float alpha = emit_f[(size_t)b * 512 * 32 + j] + emit_b[(size_t)b * 512 * 32 + j];
  for (int s = 1; s < len; s++) {
    float e = emit_f[((size_t)b * 512 + s) * 32 + j] + emit_b[((size_t)b * 512 + s) * 32 + j];
    float v[16]; float m1 = -1e30f;
#pragma unroll
    for (int ii = 0; ii < 16; ii++) { v[ii] = __shfl(alpha, i0 + ii) + tr[ii]; m1 = fmaxf(m1, v[ii]); }
    float m2 = fmaxf(m1, __shfl_xor(m1, 32));
    float sum = 0.f;
#pragma unroll
    for (int ii = 0; ii < 16; ii++) sum += __builtin_amdgcn_exp2f((v[ii] - m2) * LOG2E);
    sum += __shfl_xor(sum, 32);
    alpha = m2 + LN2 * __builtin_amdgcn_logf(sum) + e;   // amdgcn logf == log2
  }
  float mz = alpha;
#pragma unroll
  for (int m = 16; m; m >>= 1) mz = fmaxf(mz, __shfl_xor(mz, m));
  float sz = __builtin_amdgcn_exp2f((alpha - mz) * LOG2E);
#pragma unroll
  for (int m = 16; m; m >>= 1) sz += __shfl_xor(sz, m);
  float logz = mz + LN2 * __builtin_amdgcn_logf(sz);
  if (lane == 0) out[b] = logz - rs;
}

// ---------------- launch ----------------
extern "C" void kernel_launch(void* const* d_in, const int* in_sizes, int n_in,
                              void* d_out, int out_size, void* d_ws, size_t ws_size,
                              hipStream_t stream) {
  const float* emb   = (const float*)d_in[0];
  const float* Wih_f = (const float*)d_in[1];
  const float* Whh_f = (const float*)d_in[2];
  const float* bih_f = (const float*)d_in[3];
  const float* bhh_f = (const float*)d_in[4];
  const float* Wih_b = (const float*)d_in[5];
  const float* Whh_b = (const float*)d_in[6];
  const float* bih_b = (const float*)d_in[7];
  const float* bhh_b = (const float*)d_in[8];
  const float* Wout  = (const float*)d_in[9];
  const float* bout  = (const float*)d_in[10];
  const float* trans = (const float*)d_in[11];
  const int* sent = (const int*)d_in[12];
  const int* tags = (const int*)d_in[13];
  const int* lens = (const int*)d_in[14];
  float* out = (float*)d_out;

  // workspace layout (bytes): fixed 36,470,784 + gx (chunkS MB)
  char* ws = (char*)d_ws;
  float*          emit_f  = (float*)(ws);                        // 16,777,216
  float*          emit_b  = (float*)(ws + 16777216);             // 16,777,216
  unsigned short* wih_bf  = (unsigned short*)(ws + 33554432);    //  1,048,576
  unsigned short* whh_bf  = (unsigned short*)(ws + 34603008);    //  1,048,576
  unsigned short* wout_bf = (unsigned short*)(ws + 35651584);    //     32,768
  unsigned short* h_state = (unsigned short*)(ws + 35684352);    //    262,144
  float*          c_state = (float*)(ws + 35946496);             //    524,288
  unsigned short* gx      = (unsigned short*)(ws + 36470784);

  size_t fixed = 36470784ull;
  int chunkS = 512;  // gx bytes = chunkS * 1 MB (2 dirs x 256 b x 1024 g x 2B per step)
  while (chunkS > 32 && fixed + (size_t)chunkS * 1048576ull > ws_size) chunkS >>= 1;
  if (fixed + (size_t)chunkS * 1048576ull > ws_size) return;

  // dynamic LDS for lstm_rec: 128 KB wlds + 16,896 B hbuf
  size_t rec_lds = 131072 + 16896;
  hipFuncSetAttribute((const void*)lstm_rec,
                      hipFuncAttributeMaxDynamicSharedMemorySize, (int)rec_lds);

  cvt_weights<<<1040, 256, 0, stream>>>(Wih_f, Wih_b, Whh_f, Whh_b, Wout,
                                        wih_bf, whh_bf, wout_bf);
  int nch = 512 / chunkS;
  for (int c = 0; c < nch; c++) {
    gx_gemm<<<dim3(chunkS * 2, 2), 512, 0, stream>>>(
        emb, sent, lens, wih_bf, bih_f, bhh_f, bih_b, bhh_b, gx, c * chunkS, chunkS);
    lstm_rec<<<32, 512, rec_lds, stream>>>(
        gx, whh_bf, wout_bf, bout, lens, emit_f, emit_b, h_state, c_state,
        c * chunkS, chunkS, c == 0 ? 1 : 0);
  }
  crf_kernel<<<256, 64, 0, stream>>>(emit_f, emit_b, trans, tags, lens, out);
}

// Round 4
// 2363.437 us; speedup vs baseline: 5.4368x; 1.4806x over previous
//
#include <hip/hip_runtime.h>
#include <hip/hip_bf16.h>

// BiLSTM-CRF forward, MI355X gfx950.
// B=256, S=512, E=256, H=256, G=4H=1024, T=32, PAD=49999.
//
// Round-4 structure:
//   K0 cvt_weights : fp32 -> bf16 for W_ih(2), W_hh(2), W_out
//   K1 embed_gather: x_bf[b][s][e] bf16
//   K2 lstm_rec    : 128 WGs x 256 thr. WG = (group of 16 sentences, dir, unit-chunk of 64).
//                    Per wave: 64 gate rows; W_ih + W_hh rows FULLY VGPR-resident
//                    (128+128 regs). Per step: acc = bias + W_ih@x(s_eff)^T + W_hh@h^T,
//                    gates, h-chunk exchanged between the 4 quad WGs via agent-scope
//                    atomics in global (double-buffered parity, exact-match flags).
//                    x frags prefetched one step ahead. u=0 WG fuses emission
//                    (atomicAdd into single zeroed emit buffer; dir0 adds b_out).
//   K3 crf_kernel  : real-path score + CRF forward (T=32) per sentence.

typedef __bf16 bf16x8 __attribute__((ext_vector_type(8)));
typedef float f32x4 __attribute__((ext_vector_type(4)));
typedef unsigned int uint4v __attribute__((ext_vector_type(4)));

__device__ __forceinline__ unsigned short f2bf(float f) {
  union { float f; unsigned int u; } v; v.f = f;
  unsigned int r = v.u + 0x7fffu + ((v.u >> 16) & 1u);   // RNE
  return (unsigned short)(r >> 16);
}
__device__ __forceinline__ float fsig(float x) {
  float e = __builtin_amdgcn_exp2f(-1.4426950408889634f * x);
  return __builtin_amdgcn_rcpf(1.0f + e);
}
__device__ __forceinline__ float ftanh(float x) {
  float e = __builtin_amdgcn_exp2f(2.8853900817779268f * x);
  return 1.0f - 2.0f * __builtin_amdgcn_rcpf(e + 1.0f);
}

// ---------------- K0: weight conversion fp32 -> bf16 ----------------
__global__ void cvt_weights(const float* __restrict__ wih_f, const float* __restrict__ wih_b,
                            const float* __restrict__ whh_f, const float* __restrict__ whh_b,
                            const float* __restrict__ wo,
                            unsigned short* __restrict__ wih, unsigned short* __restrict__ whh,
                            unsigned short* __restrict__ wout) {
  int t = blockIdx.x * 256 + threadIdx.x;
  int i = t * 4;
  const float* src; unsigned short* dst; int off;
  if (i < 524288)       { src = (i < 262144) ? wih_f : wih_b; off = i & 262143; dst = wih + i; }
  else if (i < 1048576) { int k = i - 524288;  src = (k < 262144) ? whh_f : whh_b; off = k & 262143; dst = whh + k; }
  else if (i < 1064960) { int k = i - 1048576; src = wo; off = k; dst = wout + k; }
  else return;
  f32x4 v = *(const f32x4*)(src + off);
  uint2 p;
  p.x = f2bf(v[0]) | ((unsigned int)f2bf(v[1]) << 16);
  p.y = f2bf(v[2]) | ((unsigned int)f2bf(v[3]) << 16);
  *(uint2*)dst = p;
}

// ---------------- K1: embedding gather -> bf16 ----------------
__global__ void embed_gather(const float* __restrict__ emb, const int* __restrict__ sent,
                             unsigned short* __restrict__ xo) {
  int tok  = blockIdx.x * 4 + (threadIdx.x >> 6);   // b*512+s
  int lane = threadIdx.x & 63;
  int tkn = sent[tok];
  f32x4 v = *(const f32x4*)(emb + (size_t)tkn * 256 + lane * 4);
  uint2 o;
  o.x = f2bf(v[0]) | ((unsigned int)f2bf(v[1]) << 16);
  o.y = f2bf(v[2]) | ((unsigned int)f2bf(v[3]) << 16);
  *(uint2*)(xo + (size_t)tok * 256 + lane * 4) = o;
}

// ---------------- K2: quad-split LSTM recurrence, W fully VGPR-resident ------
// grid 128: bx = u*32 + ch; ch = grp*2 + dir (quad members differ by 32 ==
// same XCD under round-robin dispatch). 256 thr = 4 waves; wave w owns units
// [u*64 + w*16, +16), i.e. gate rows {t*256 + U0 + 0..15 : t=0..3}.
// hx: [32 ch][2 parity][1024 u64] h-exchange; flg: [32 ch][2 parity][4 u][16] u32.
__global__ __launch_bounds__(256, 1) void lstm_rec(
    const unsigned short* __restrict__ x_bf,   // [256][512][256]
    const unsigned short* __restrict__ wih,    // [2][1024][256]
    const unsigned short* __restrict__ whh,    // [2][1024][256]
    const unsigned short* __restrict__ wout,   // [32][512]
    const float* __restrict__ bih_f, const float* __restrict__ bhh_f,
    const float* __restrict__ bih_b, const float* __restrict__ bhh_b,
    const float* __restrict__ bout,
    const int* __restrict__ lens,
    float* __restrict__ emit,                  // [256][512][32] f32, pre-zeroed
    unsigned long long* __restrict__ hx,
    unsigned int* __restrict__ flg)
{
  int bx = blockIdx.x;
  int u = bx >> 5, ch = bx & 31, dir = ch & 1, grp = ch >> 1, b0 = grp * 16;
  int tid = threadIdx.x, w = tid >> 6, lane = tid & 63, col = lane & 15, q = lane >> 4;
  int maxlen = lens[b0];              // sorted descending -> group max
  int mylen  = lens[b0 + col];
  int U0 = u * 64 + w * 16;
  const unsigned short* wihb = wih + (size_t)dir * 262144;
  const unsigned short* whhb = whh + (size_t)dir * 262144;

  // ---- weights fully into registers: 32 frags each (128 VGPR each) ----
  bf16x8 wif[8][4], whf[8][4];
#pragma unroll
  for (int kt = 0; kt < 8; kt++)
#pragma unroll
    for (int t = 0; t < 4; t++) {
      size_t off = (size_t)(t * 256 + U0 + col) * 256 + kt * 32 + q * 8;
      wif[kt][t] = *(const bf16x8*)(wihb + off);
      whf[kt][t] = *(const bf16x8*)(whhb + off);
    }
  const float* bi = dir ? bih_b : bih_f;
  const float* bh = dir ? bhh_b : bhh_f;
  f32x4 bias4[4];
#pragma unroll
  for (int t = 0; t < 4; t++)
#pragma unroll
    for (int r = 0; r < 4; r++) {
      int row = t * 256 + U0 + q * 4 + r;
      bias4[t][r] = bi[row] + bh[row];
    }

  // ---- emission weights (u==0, waves 0-1) ----
  bool do_emit = (u == 0) && (w < 2);
  bf16x8 wof[8];
  f32x4 bo4 = (f32x4){0.f, 0.f, 0.f, 0.f};
  if (do_emit) {
#pragma unroll
    for (int kt = 0; kt < 8; kt++)
      wof[kt] = *(const bf16x8*)(wout + (size_t)(w * 16 + col) * 512 + dir * 256 + kt * 32 + q * 8);
    if (dir == 0) {
#pragma unroll
      for (int r = 0; r < 4; r++) bo4[r] = bout[w * 16 + q * 4 + r];
    }
  }

  unsigned long long* hxc = hx + (size_t)ch * 2048;   // 2 parities x 1024 u64
  unsigned int* flc = flg + ch * 128;                 // 2 parities x 4 u x 16

  // ---- x fragment prefetch for s=0 ----
  const unsigned short* xbase = x_bf + (size_t)(b0 + col) * 512 * 256;
  bf16x8 xb[8];
  {
    int se = dir ? (mylen - 1) : 0;
    const unsigned short* xp = xbase + (size_t)se * 256;
#pragma unroll
    for (int kt = 0; kt < 8; kt++) xb[kt] = *(const bf16x8*)(xp + kt * 32 + q * 8);
  }

  bf16x8 hbf[8];
  float c4[4] = {0.f, 0.f, 0.f, 0.f};
  int uk = u * 8 + w * 2 + (q >> 1);
  size_t hw_idx = (size_t)(uk * 16 + col) * 2 + (q & 1);

  for (int s = 0; s < maxlen; s++) {
    f32x4 acc[4];
#pragma unroll
    for (int t = 0; t < 4; t++) acc[t] = bias4[t];
    // ---- x-part (independent of peers) ----
#pragma unroll
    for (int kt = 0; kt < 8; kt++) {
      bf16x8 xv = xb[kt];
#pragma unroll
      for (int t = 0; t < 4; t++)
        acc[t] = __builtin_amdgcn_mfma_f32_16x16x32_bf16(wif[kt][t], xv, acc[t], 0, 0, 0);
    }
    // ---- prefetch x for s+1 (overlaps the peer wait) ----
    {
      int sn = (s + 1 < maxlen) ? s + 1 : s;
      int se = dir ? ((sn < mylen) ? (mylen - 1 - sn) : sn) : sn;
      const unsigned short* xp = xbase + (size_t)se * 256;
#pragma unroll
      for (int kt = 0; kt < 8; kt++) xb[kt] = *(const bf16x8*)(xp + kt * 32 + q * 8);
    }
    // ---- wait for h(s-1) from quad peers, then h-part + fused emission ----
    if (s > 0) {
      int par = (s - 1) & 1;
      if (tid < 4) {
        unsigned want = (unsigned)s;
        int fi = (par * 4 + tid) * 16;
        int guard = 0;
        while (__hip_atomic_load(&flc[fi], __ATOMIC_ACQUIRE, __HIP_MEMORY_SCOPE_AGENT) != want) {
          __builtin_amdgcn_s_sleep(2);
          if (++guard > 50000000) break;
        }
      }
      __syncthreads();
      const unsigned long long* hb64 = hxc + (size_t)par * 1024;
#pragma unroll
      for (int kt = 0; kt < 8; kt++) {
        size_t i0 = (size_t)((kt * 4 + q) * 16 + col) * 2;
        unsigned long long a = __hip_atomic_load(hb64 + i0,     __ATOMIC_RELAXED, __HIP_MEMORY_SCOPE_AGENT);
        unsigned long long b = __hip_atomic_load(hb64 + i0 + 1, __ATOMIC_RELAXED, __HIP_MEMORY_SCOPE_AGENT);
        uint4v pk;
        pk[0] = (unsigned int)a; pk[1] = (unsigned int)(a >> 32);
        pk[2] = (unsigned int)b; pk[3] = (unsigned int)(b >> 32);
        hbf[kt] = __builtin_bit_cast(bf16x8, pk);
      }
#pragma unroll
      for (int kt = 0; kt < 8; kt++) {
        bf16x8 hv = hbf[kt];
#pragma unroll
        for (int t = 0; t < 4; t++)
          acc[t] = __builtin_amdgcn_mfma_f32_16x16x32_bf16(whf[kt][t], hv, acc[t], 0, 0, 0);
      }
      if (do_emit) {          // emission for step s-1 (h(s-1) frags in regs)
        f32x4 ea = bo4;
#pragma unroll
        for (int kt = 0; kt < 8; kt++)
          ea = __builtin_amdgcn_mfma_f32_16x16x32_bf16(wof[kt], hbf[kt], ea, 0, 0, 0);
        if (s - 1 < mylen) {
          int pos = dir ? (mylen - s) : (s - 1);
          float* dst = emit + (((size_t)(b0 + col) * 512 + pos) * 32 + w * 16 + q * 4);
#pragma unroll
          for (int r = 0; r < 4; r++) atomicAdd(dst + r, ea[r]);
        }
      }
    }
    // ---- gates -> h chunk -> exchange ----
    float hv[4];
#pragma unroll
    for (int r = 0; r < 4; r++) {
      float ig = acc[0][r], fg = acc[1][r], gg = acc[2][r], og = acc[3][r];
      float cn = fsig(fg) * c4[r] + fsig(ig) * ftanh(gg);
      c4[r] = cn;
      hv[r] = fsig(og) * ftanh(cn);
    }
    unsigned long long hp =
        (unsigned long long)(f2bf(hv[0]) | ((unsigned int)f2bf(hv[1]) << 16)) |
        ((unsigned long long)(f2bf(hv[2]) | ((unsigned int)f2bf(hv[3]) << 16)) << 32);
    __hip_atomic_store(hxc + (size_t)(s & 1) * 1024 + hw_idx, hp,
                       __ATOMIC_RELAXED, __HIP_MEMORY_SCOPE_AGENT);
    __syncthreads();          // drains each wave's vmcnt before barrier
    if (tid == 0)
      __hip_atomic_store(&flc[((s & 1) * 4 + u) * 16], (unsigned)(s + 1),
                         __ATOMIC_RELEASE, __HIP_MEMORY_SCOPE_AGENT);
  }

  // ---- final emission for h(maxlen-1) ----
  if (u == 0) {
    int s = maxlen;
    int par = (s - 1) & 1;
    if (tid < 4) {
      unsigned want = (unsigned)s;
      int fi = (par * 4 + tid) * 16;
      int guard = 0;
      while (__hip_atomic_load(&flc[fi], __ATOMIC_ACQUIRE, __HIP_MEMORY_SCOPE_AGENT) != want) {
        __builtin_amdgcn_s_sleep(2);
        if (++guard > 50000000) break;
      }
    }
    __syncthreads();
    if (do_emit) {
      const unsigned long long* hb64 = hxc + (size_t)par * 1024;
      f32x4 ea = bo4;
#pragma unroll
      for (int kt = 0; kt < 8; kt++) {
        size_t i0 = (size_t)((kt * 4 + q) * 16 + col) * 2;
        unsigned long long a = __hip_atomic_load(hb64 + i0,     __ATOMIC_RELAXED, __HIP_MEMORY_SCOPE_AGENT);
        unsigned long long b = __hip_atomic_load(hb64 + i0 + 1, __ATOMIC_RELAXED, __HIP_MEMORY_SCOPE_AGENT);
        uint4v pk;
        pk[0] = (unsigned int)a; pk[1] = (unsigned int)(a >> 32);
        pk[2] = (unsigned int)b; pk[3] = (unsigned int)(b >> 32);
        bf16x8 hv = __builtin_bit_cast(bf16x8, pk);
        ea = __builtin_amdgcn_mfma_f32_16x16x32_bf16(wof[kt], hv, ea, 0, 0, 0);
      }
      if (s - 1 < mylen) {
        int pos = dir ? (mylen - s) : (s - 1);
        float* dst = emit + (((size_t)(b0 + col) * 512 + pos) * 32 + w * 16 + q * 4);
#pragma unroll
      for (int r = 0; r < 4; r++) atomicAdd(dst + r, ea[r]);
      }
    }
  }
}

// ---------------- K3: real-path score + CRF forward ----------------
__global__ void crf_kernel(const float* __restrict__ emit,
                           const float* __restrict__ trans, const int* __restrict__ tags,
                           const int* __restrict__ lens, float* __restrict__ out) {
  const float LOG2E = 1.4426950408889634f, LN2 = 0.6931471805599453f;
  int b = blockIdx.x, lane = threadIdx.x;
  int len = lens[b];
  const int* tg = tags + b * 512;

  float rs = 0.f;
  for (int s = lane; s < len; s += 64) {
    int t1 = tg[s];
    float e = emit[((size_t)b * 512 + s) * 32 + t1];
    if (s > 0) e += trans[tg[s - 1] * 32 + t1];
    rs += e;
  }
#pragma unroll
  for (int m = 32; m; m >>= 1) rs += __shfl_xor(rs, m);

  int j = lane & 31, half = lane >> 5, i0 = half * 16;
  float tr[16];
#pragma unroll
  for (int ii = 0; ii < 16; ii++) tr[ii] = trans[(i0 + ii) * 32 + j];
  float alpha = emit[(size_t)b * 512 * 32 + j];
  for (int s = 1; s < len; s++) {
    float e = emit[((size_t)b * 512 + s) * 32 + j];
    float v[16]; float m1 = -1e30f;
#pragma unroll
    for (int ii = 0; ii < 16; ii++) { v[ii] = __shfl(alpha, i0 + ii) + tr[ii]; m1 = fmaxf(m1, v[ii]); }
    float m2 = fmaxf(m1, __shfl_xor(m1, 32));
    float sum = 0.f;
#pragma unroll
    for (int ii = 0; ii < 16; ii++) sum += __builtin_amdgcn_exp2f((v[ii] - m2) * LOG2E);
    sum += __shfl_xor(sum, 32);
    alpha = m2 + LN2 * __builtin_amdgcn_logf(sum) + e;   // amdgcn logf == log2
  }
  float mz = alpha;
#pragma unroll
  for (int m = 16; m; m >>= 1) mz = fmaxf(mz, __shfl_xor(mz, m));
  float sz = __builtin_amdgcn_exp2f((alpha - mz) * LOG2E);
#pragma unroll
  for (int m = 16; m; m >>= 1) sz += __shfl_xor(sz, m);
  float logz = mz + LN2 * __builtin_amdgcn_logf(sz);
  if (lane == 0) out[b] = logz - rs;
}

// ---------------- launch ----------------
extern "C" void kernel_launch(void* const* d_in, const int* in_sizes, int n_in,
                              void* d_out, int out_size, void* d_ws, size_t ws_size,
                              hipStream_t stream) {
  const float* emb   = (const float*)d_in[0];
  const float* Wih_f = (const float*)d_in[1];
  const float* Whh_f = (const float*)d_in[2];
  const float* bih_f = (const float*)d_in[3];
  const float* bhh_f = (const float*)d_in[4];
  const float* Wih_b = (const float*)d_in[5];
  const float* Whh_b = (const float*)d_in[6];
  const float* bih_b = (const float*)d_in[7];
  const float* bhh_b = (const float*)d_in[8];
  const float* Wout  = (const float*)d_in[9];
  const float* bout  = (const float*)d_in[10];
  const float* trans = (const float*)d_in[11];
  const int* sent = (const int*)d_in[12];
  const int* tags = (const int*)d_in[13];
  const int* lens = (const int*)d_in[14];
  float* out = (float*)d_out;

  // workspace layout (bytes), total 86,556,672
  char* ws = (char*)d_ws;
  if (ws_size < 86556672ull) return;
  unsigned short* x_bf    = (unsigned short*)(ws);                // 67,108,864
  float*          emit    = (float*)(ws + 67108864);              // 16,777,216
  unsigned short* wih_bf  = (unsigned short*)(ws + 83886080);     //  1,048,576
  unsigned short* whh_bf  = (unsigned short*)(ws + 84934656);     //  1,048,576
  unsigned short* wout_bf = (unsigned short*)(ws + 85983232);     //     32,768
  unsigned long long* hx  = (unsigned long long*)(ws + 86016000); //    524,288
  unsigned int*   flg     = (unsigned int*)(ws + 86540288);       //     16,384

  hipMemsetAsync(emit, 0, 16777216, stream);
  cvt_weights<<<1040, 256, 0, stream>>>(Wih_f, Wih_b, Whh_f, Whh_b, Wout,
                                        wih_bf, whh_bf, wout_bf);
  embed_gather<<<32768, 256, 0, stream>>>(emb, sent, x_bf);
  lstm_rec<<<128, 256, 0, stream>>>(x_bf, wih_bf, whh_bf, wout_bf,
                                    bih_f, bhh_f, bih_b, bhh_b, bout, lens,
                                    emit, hx, flg);
  crf_kernel<<<256, 64, 0, stream>>>(emit, trans, tags, lens, out);
}

// Round 5
// 2305.690 us; speedup vs baseline: 5.5730x; 1.0250x over previous
//
#include <hip/hip_runtime.h>
#include <hip/hip_bf16.h>

// BiLSTM-CRF forward, MI355X gfx950.
// B=256, S=512, E=256, H=256, G=4H=1024, T=32, PAD=49999.
//
// Round-5 structure:
//   K0 cvt_weights : fp32 -> bf16 for W_ih(2), W_hh(2), W_out
//   K1 embed_gather: x_bf[b][s][e] bf16
//   K2 lstm_rec    : 128 WGs x 256 thr. WG = (16-sentence group, dir, unit-chunk of 64).
//                    W_ih + W_hh rows fully VGPR-resident per wave (128+128 regs).
//                    Per step: acc = bias + W_ih@x^T (prefetched x) + W_hh@h^T;
//                    h exchanged between quad WGs via agent-scope global
//                    (double-buffered parity, exact-match flags). Emission (u=0,
//                    waves 0-1) computed AFTER the flag release -> off critical path;
//                    plain bf16 stores into emit_f/emit_b (no atomics, no memset).
//   K3 crf_kernel  : real-path score + CRF forward (T=32); emit = emit_f + emit_b.

typedef __bf16 bf16x8 __attribute__((ext_vector_type(8)));
typedef float f32x4 __attribute__((ext_vector_type(4)));
typedef unsigned int uint4v __attribute__((ext_vector_type(4)));

__device__ __forceinline__ unsigned short f2bf(float f) {
  union { float f; unsigned int u; } v; v.f = f;
  unsigned int r = v.u + 0x7fffu + ((v.u >> 16) & 1u);   // RNE
  return (unsigned short)(r >> 16);
}
__device__ __forceinline__ float bf2f(unsigned int lo16) {
  union { unsigned int u; float f; } v; v.u = lo16 << 16;
  return v.f;
}
__device__ __forceinline__ float fsig(float x) {
  float e = __builtin_amdgcn_exp2f(-1.4426950408889634f * x);
  return __builtin_amdgcn_rcpf(1.0f + e);
}
__device__ __forceinline__ float ftanh(float x) {
  float e = __builtin_amdgcn_exp2f(2.8853900817779268f * x);
  return 1.0f - 2.0f * __builtin_amdgcn_rcpf(e + 1.0f);
}

// ---------------- K0: weight conversion fp32 -> bf16 ----------------
__global__ void cvt_weights(const float* __restrict__ wih_f, const float* __restrict__ wih_b,
                            const float* __restrict__ whh_f, const float* __restrict__ whh_b,
                            const float* __restrict__ wo,
                            unsigned short* __restrict__ wih, unsigned short* __restrict__ whh,
                            unsigned short* __restrict__ wout) {
  int t = blockIdx.x * 256 + threadIdx.x;
  int i = t * 4;
  const float* src; unsigned short* dst; int off;
  if (i < 524288)       { src = (i < 262144) ? wih_f : wih_b; off = i & 262143; dst = wih + i; }
  else if (i < 1048576) { int k = i - 524288;  src = (k < 262144) ? whh_f : whh_b; off = k & 262143; dst = whh + k; }
  else if (i < 1064960) { int k = i - 1048576; src = wo; off = k; dst = wout + k; }
  else return;
  f32x4 v = *(const f32x4*)(src + off);
  uint2 p;
  p.x = f2bf(v[0]) | ((unsigned int)f2bf(v[1]) << 16);
  p.y = f2bf(v[2]) | ((unsigned int)f2bf(v[3]) << 16);
  *(uint2*)dst = p;
}

// ---------------- K1: embedding gather -> bf16 ----------------
__global__ void embed_gather(const float* __restrict__ emb, const int* __restrict__ sent,
                             unsigned short* __restrict__ xo) {
  int tok  = blockIdx.x * 4 + (threadIdx.x >> 6);   // b*512+s
  int lane = threadIdx.x & 63;
  int tkn = sent[tok];
  f32x4 v = *(const f32x4*)(emb + (size_t)tkn * 256 + lane * 4);
  uint2 o;
  o.x = f2bf(v[0]) | ((unsigned int)f2bf(v[1]) << 16);
  o.y = f2bf(v[2]) | ((unsigned int)f2bf(v[3]) << 16);
  *(uint2*)(xo + (size_t)tok * 256 + lane * 4) = o;
}

// ---------------- K2: quad-split LSTM recurrence, W fully VGPR-resident ------
// grid 128: bx = u*32 + ch; ch = grp*2 + dir. Quad members bx, bx+32, .. land on
// the same XCD under round-robin (32 % 8 == 0) -- speed heuristic only; agent
// scope guarantees correctness regardless. 256 thr = 4 waves; wave w owns units
// [u*64 + w*16, +16): gate rows {g*256 + U0 + 0..15 : g=0..3}.
// hx: [32 ch][2 parity][1024 u64]; flg: [32 ch][2 parity][4 u][16] u32.
__global__ __launch_bounds__(256, 1) void lstm_rec(
    const unsigned short* __restrict__ x_bf,   // [256][512][256]
    const unsigned short* __restrict__ wih,    // [2][1024][256]
    const unsigned short* __restrict__ whh,    // [2][1024][256]
    const unsigned short* __restrict__ wout,   // [32][512]
    const float* __restrict__ bih_f, const float* __restrict__ bhh_f,
    const float* __restrict__ bih_b, const float* __restrict__ bhh_b,
    const float* __restrict__ bout,
    const int* __restrict__ lens,
    unsigned short* __restrict__ emit_f,       // [256][512][32] bf16
    unsigned short* __restrict__ emit_b,       // [256][512][32] bf16
    unsigned long long* __restrict__ hx,
    unsigned int* __restrict__ flg)
{
  int bx = blockIdx.x;
  int u = bx >> 5, ch = bx & 31, dir = ch & 1, grp = ch >> 1, b0 = grp * 16;
  int tid = threadIdx.x, w = tid >> 6, lane = tid & 63, col = lane & 15, q = lane >> 4;
  int maxlen = lens[b0];              // sorted descending -> group max
  int mylen  = lens[b0 + col];
  int U0 = u * 64 + w * 16;
  const unsigned short* wihb = wih + (size_t)dir * 262144;
  const unsigned short* whhb = whh + (size_t)dir * 262144;

  // ---- weights fully into registers: 32 frags each ----
  bf16x8 wif[8][4], whf[8][4];
#pragma unroll
  for (int kt = 0; kt < 8; kt++)
#pragma unroll
    for (int t = 0; t < 4; t++) {
      size_t off = (size_t)(t * 256 + U0 + col) * 256 + kt * 32 + q * 8;
      wif[kt][t] = *(const bf16x8*)(wihb + off);
      whf[kt][t] = *(const bf16x8*)(whhb + off);
    }
  const float* bi = dir ? bih_b : bih_f;
  const float* bh = dir ? bhh_b : bhh_f;
  f32x4 bias4[4];
#pragma unroll
  for (int t = 0; t < 4; t++)
#pragma unroll
    for (int r = 0; r < 4; r++) {
      int row = t * 256 + U0 + q * 4 + r;
      bias4[t][r] = bi[row] + bh[row];
    }

  // ---- emission weights (u==0, waves 0-1): dir selects W_out half ----
  bool do_emit = (u == 0) && (w < 2);
  bf16x8 wof[8];
  f32x4 bo4 = (f32x4){0.f, 0.f, 0.f, 0.f};
  if (do_emit) {
#pragma unroll
    for (int kt = 0; kt < 8; kt++)
      wof[kt] = *(const bf16x8*)(wout + (size_t)(w * 16 + col) * 512 + dir * 256 + kt * 32 + q * 8);
    if (dir == 0) {
#pragma unroll
      for (int r = 0; r < 4; r++) bo4[r] = bout[w * 16 + q * 4 + r];
    }
  }
  unsigned short* ebase = dir ? emit_b : emit_f;

  unsigned long long* hxc = hx + (size_t)ch * 2048;   // 2 parities x 1024 u64
  unsigned int* flc = flg + ch * 128;                 // 2 parities x 4 u x 16

  // ---- x fragment prefetch for s=0 ----
  const unsigned short* xbase = x_bf + (size_t)(b0 + col) * 512 * 256;
  bf16x8 xb[8];
  {
    int se = dir ? (mylen - 1) : 0;
    const unsigned short* xp = xbase + (size_t)se * 256;
#pragma unroll
    for (int kt = 0; kt < 8; kt++) xb[kt] = *(const bf16x8*)(xp + kt * 32 + q * 8);
  }

  bf16x8 hbf[8];
  float c4[4] = {0.f, 0.f, 0.f, 0.f};
  int uk = u * 8 + w * 2 + (q >> 1);
  size_t hw_idx = (size_t)(uk * 16 + col) * 2 + (q & 1);

  for (int s = 0; s < maxlen; s++) {
    f32x4 acc[4];
#pragma unroll
    for (int t = 0; t < 4; t++) acc[t] = bias4[t];
    // ---- x-part (independent of peers) ----
#pragma unroll
    for (int kt = 0; kt < 8; kt++) {
      bf16x8 xv = xb[kt];
#pragma unroll
      for (int t = 0; t < 4; t++)
        acc[t] = __builtin_amdgcn_mfma_f32_16x16x32_bf16(wif[kt][t], xv, acc[t], 0, 0, 0);
    }
    // ---- prefetch x for s+1 (overlaps the peer wait) ----
    {
      int sn = (s + 1 < maxlen) ? s + 1 : s;
      int se = dir ? ((sn < mylen) ? (mylen - 1 - sn) : sn) : sn;
      const unsigned short* xp = xbase + (size_t)se * 256;
#pragma unroll
      for (int kt = 0; kt < 8; kt++) xb[kt] = *(const bf16x8*)(xp + kt * 32 + q * 8);
    }
    // ---- wait for h(s-1) from quad peers, then h-part ----
    if (s > 0) {
      int par = (s - 1) & 1;
      if (tid < 4 && tid != u) {
        unsigned want = (unsigned)s;
        int fi = (par * 4 + tid) * 16;
        int guard = 0;
        while (__hip_atomic_load(&flc[fi], __ATOMIC_ACQUIRE, __HIP_MEMORY_SCOPE_AGENT) != want) {
          if (++guard > 100000000) break;
        }
      }
      __syncthreads();
      const unsigned long long* hb64 = hxc + (size_t)par * 1024;
#pragma unroll
      for (int kt = 0; kt < 8; kt++) {
        size_t i0 = (size_t)((kt * 4 + q) * 16 + col) * 2;
        unsigned long long a = __hip_atomic_load(hb64 + i0,     __ATOMIC_RELAXED, __HIP_MEMORY_SCOPE_AGENT);
        unsigned long long b = __hip_atomic_load(hb64 + i0 + 1, __ATOMIC_RELAXED, __HIP_MEMORY_SCOPE_AGENT);
        uint4v pk;
        pk[0] = (unsigned int)a; pk[1] = (unsigned int)(a >> 32);
        pk[2] = (unsigned int)b; pk[3] = (unsigned int)(b >> 32);
        hbf[kt] = __builtin_bit_cast(bf16x8, pk);
      }
#pragma unroll
      for (int kt = 0; kt < 8; kt++) {
        bf16x8 hv = hbf[kt];
#pragma unroll
        for (int t = 0; t < 4; t++)
          acc[t] = __builtin_amdgcn_mfma_f32_16x16x32_bf16(whf[kt][t], hv, acc[t], 0, 0, 0);
      }
    }
    // ---- gates -> h chunk -> exchange ----
    float hv[4];
#pragma unroll
    for (int r = 0; r < 4; r++) {
      float ig = acc[0][r], fg = acc[1][r], gg = acc[2][r], og = acc[3][r];
      float cn = fsig(fg) * c4[r] + fsig(ig) * ftanh(gg);
      c4[r] = cn;
      hv[r] = fsig(og) * ftanh(cn);
    }
    unsigned long long hp =
        (unsigned long long)(f2bf(hv[0]) | ((unsigned int)f2bf(hv[1]) << 16)) |
        ((unsigned long long)(f2bf(hv[2]) | ((unsigned int)f2bf(hv[3]) << 16)) << 32);
    __hip_atomic_store(hxc + (size_t)(s & 1) * 1024 + hw_idx, hp,
                       __ATOMIC_RELAXED, __HIP_MEMORY_SCOPE_AGENT);
    __syncthreads();          // per-wave vmcnt(0) drain -> all WG stores acked
    if (tid == 0)
      __hip_atomic_store(&flc[((s & 1) * 4 + u) * 16], (unsigned)(s + 1),
                         __ATOMIC_RELEASE, __HIP_MEMORY_SCOPE_AGENT);

    // ---- fused emission for step s-1, AFTER flag: off the critical path ----
    if (s > 0 && do_emit) {
      f32x4 ea = bo4;
#pragma unroll
      for (int kt = 0; kt < 8; kt++)
        ea = __builtin_amdgcn_mfma_f32_16x16x32_bf16(wof[kt], hbf[kt], ea, 0, 0, 0);
      if (s - 1 < mylen) {
        int pos = dir ? (mylen - s) : (s - 1);
        unsigned short* dst = ebase + (((size_t)(b0 + col) * 512 + pos) * 32 + w * 16 + q * 4);
        uint2 pk;
        pk.x = f2bf(ea[0]) | ((unsigned int)f2bf(ea[1]) << 16);
        pk.y = f2bf(ea[2]) | ((unsigned int)f2bf(ea[3]) << 16);
        *(uint2*)dst = pk;
      }
    }
  }

  // ---- final emission for h(maxlen-1) ----
  if (u == 0) {
    int s = maxlen;
    int par = (s - 1) & 1;
    if (tid < 4 && tid != u) {
      unsigned want = (unsigned)s;
      int fi = (par * 4 + tid) * 16;
      int guard = 0;
      while (__hip_atomic_load(&flc[fi], __ATOMIC_ACQUIRE, __HIP_MEMORY_SCOPE_AGENT) != want) {
        if (++guard > 100000000) break;
      }
    }
    __syncthreads();
    if (do_emit) {
      const unsigned long long* hb64 = hxc + (size_t)par * 1024;
      f32x4 ea = bo4;
#pragma unroll
      for (int kt = 0; kt < 8; kt++) {
        size_t i0 = (size_t)((kt * 4 + q) * 16 + col) * 2;
        unsigned long long a = __hip_atomic_load(hb64 + i0,     __ATOMIC_RELAXED, __HIP_MEMORY_SCOPE_AGENT);
        unsigned long long b = __hip_atomic_load(hb64 + i0 + 1, __ATOMIC_RELAXED, __HIP_MEMORY_SCOPE_AGENT);
        uint4v pk;
        pk[0] = (unsigned int)a; pk[1] = (unsigned int)(a >> 32);
        pk[2] = (unsigned int)b; pk[3] = (unsigned int)(b >> 32);
        bf16x8 hv2 = __builtin_bit_cast(bf16x8, pk);
        ea = __builtin_amdgcn_mfma_f32_16x16x32_bf16(wof[kt], hv2, ea, 0, 0, 0);
      }
      if (s - 1 < mylen) {
        int pos = dir ? (mylen - s) : (s - 1);
        unsigned short* dst = ebase + (((size_t)(b0 + col) * 512 + pos) * 32 + w * 16 + q * 4);
        uint2 pk;
        pk.x = f2bf(ea[0]) | ((unsigned int)f2bf(ea[1]) << 16);
        pk.y = f2bf(ea[2]) | ((unsigned int)f2bf(ea[3]) << 16);
        *(uint2*)dst = pk;
      }
    }
  }
}

// ---------------- K3: real-path score + CRF forward (bf16 emit in) ----------------
__global__ void crf_kernel(const unsigned short* __restrict__ emit_f,
                           const unsigned short* __restrict__ emit_b,
                           const float* __restrict__ trans, const int* __restrict__ tags,
                           const int* __restrict__ lens, float* __restrict__ out) {
  const float LOG2E = 1.4426950408889634f, LN2 = 0.6931471805599453f;
  int b = blockIdx.x, lane = threadIdx.x;
  int len = lens[b];
  const int* tg = tags + b * 512;

  float rs = 0.f;
  for (int s = lane; s < len; s += 64) {
    int t1 = tg[s];
    size_t idx = ((size_t)b * 512 + s) * 32 + t1;
    float e = bf2f(emit_f[idx]) + bf2f(emit_b[idx]);
    if (s > 0) e += trans[tg[s - 1] * 32 + t1];
    rs += e;
  }
#pragma unroll
  for (int m = 32; m; m >>= 1) rs += __shfl_xor(rs, m);

  int j = lane & 31, half = lane >> 5, i0 = half * 16;
  float tr[16];
#pragma unroll
  for (int ii = 0; ii < 16; ii++) tr[ii] = trans[(i0 + ii) * 32 + j];
  float alpha = bf2f(emit_f[(size_t)b * 512 * 32 + j]) + bf2f(emit_b[(size_t)b * 512 * 32 + j]);
  for (int s = 1; s < len; s++) {
    size_t idx = ((size_t)b * 512 + s) * 32 + j;
    float e = bf2f(emit_f[idx]) + bf2f(emit_b[idx]);
    float v[16]; float m1 = -1e30f;
#pragma unroll
    for (int ii = 0; ii < 16; ii++) { v[ii] = __shfl(alpha, i0 + ii) + tr[ii]; m1 = fmaxf(m1, v[ii]); }
    float m2 = fmaxf(m1, __shfl_xor(m1, 32));
    float sum = 0.f;
#pragma unroll
    for (int ii = 0; ii < 16; ii++) sum += __builtin_amdgcn_exp2f((v[ii] - m2) * LOG2E);
    sum += __shfl_xor(sum, 32);
    alpha = m2 + LN2 * __builtin_amdgcn_logf(sum) + e;   // amdgcn logf == log2
  }
  float mz = alpha;
#pragma unroll
  for (int m = 16; m; m >>= 1) mz = fmaxf(mz, __shfl_xor(mz, m));
  float sz = __builtin_amdgcn_exp2f((alpha - mz) * LOG2E);
#pragma unroll
  for (int m = 16; m; m >>= 1) sz += __shfl_xor(sz, m);
  float logz = mz + LN2 * __builtin_amdgcn_logf(sz);
  if (lane == 0) out[b] = logz - rs;
}

// ---------------- launch ----------------
extern "C" void kernel_launch(void* const* d_in, const int* in_sizes, int n_in,
                              void* d_out, int out_size, void* d_ws, size_t ws_size,
                              hipStream_t stream) {
  const float* emb   = (const float*)d_in[0];
  const float* Wih_f = (const float*)d_in[1];
  const float* Whh_f = (const float*)d_in[2];
  const float* bih_f = (const float*)d_in[3];
  const float* bhh_f = (const float*)d_in[4];
  const float* Wih_b = (const float*)d_in[5];
  const float* Whh_b = (const float*)d_in[6];
  const float* bih_b = (const float*)d_in[7];
  const float* bhh_b = (const float*)d_in[8];
  const float* Wout  = (const float*)d_in[9];
  const float* bout  = (const float*)d_in[10];
  const float* trans = (const float*)d_in[11];
  const int* sent = (const int*)d_in[12];
  const int* tags = (const int*)d_in[13];
  const int* lens = (const int*)d_in[14];
  float* out = (float*)d_out;

  // workspace layout (bytes), total 86,556,672
  char* ws = (char*)d_ws;
  if (ws_size < 86556672ull) return;
  unsigned short* x_bf    = (unsigned short*)(ws);                // 67,108,864
  unsigned short* emit_f  = (unsigned short*)(ws + 67108864);     //  8,388,608
  unsigned short* emit_b  = (unsigned short*)(ws + 75497472);     //  8,388,608
  unsigned short* wih_bf  = (unsigned short*)(ws + 83886080);     //  1,048,576
  unsigned short* whh_bf  = (unsigned short*)(ws + 84934656);     //  1,048,576
  unsigned short* wout_bf = (unsigned short*)(ws + 85983232);     //     32,768
  unsigned long long* hx  = (unsigned long long*)(ws + 86016000); //    524,288
  unsigned int*   flg     = (unsigned int*)(ws + 86540288);       //     16,384

  cvt_weights<<<1040, 256, 0, stream>>>(Wih_f, Wih_b, Whh_f, Whh_b, Wout,
                                        wih_bf, whh_bf, wout_bf);
  embed_gather<<<32768, 256, 0, stream>>>(emb, sent, x_bf);
  lstm_rec<<<128, 256, 0, stream>>>(x_bf, wih_bf, whh_bf, wout_bf,
                                    bih_f, bhh_f, bih_b, bhh_b, bout, lens,
                                    emit_f, emit_b, hx, flg);
  crf_kernel<<<256, 64, 0, stream>>>(emit_f, emit_b, trans, tags, lens, out);
}